// Round 9
// baseline (424.202 us; speedup 1.0000x reference)
//
#include <hip/hip_runtime.h>
#include <hip/hip_fp16.h>
#include <math.h>

#define N_NODES   50000
#define N_EDGES   1600000
#define NF        128
#define N_GRAPHS  64
#define N_CLASSES 10

#define NBK       391       // buckets: dst>>7, 128 nodes each (391*128 = 50048)
#define BK_SHIFT  7
#define BK_NODES  128
#define SLAB      5120      // slab capacity/bucket: mean 4096, sigma~64, +16s
#define CHUNK     4096
#define NCHUNKS   ((N_EDGES + CHUNK - 1) / CHUNK)   // 391

#define AGG_NPB   64        // nodes per k_agg block: 1024 thr, 16 lanes x 16B/node
#define AGG_GRID  ((N_NODES + AGG_NPB - 1) / AGG_NPB)   // 782

typedef _Float16 half8 __attribute__((ext_vector_type(8)));
typedef float f32x4 __attribute__((ext_vector_type(4)));

// ------------------------------------------------------------ zero / init
__global__ void k_zero(int* __restrict__ bucket_cur, float* __restrict__ sums) {
    int i = blockIdx.x * 256 + threadIdx.x;
    if (i < NBK) bucket_cur[i] = i * SLAB;
    if (i < N_GRAPHS * NF) sums[i] = 0.f;
}

// ------------- P1: scatter packed (src<<7|dstlocal) into bucket slabs
__global__ __launch_bounds__(256) void k_bscatter(const int* __restrict__ src,
                                                  const int* __restrict__ dst,
                                                  int* __restrict__ bucket_cur,
                                                  int* __restrict__ pairs) {
    __shared__ int h[NBK], rb[NBK], c2[NBK];
    int t = threadIdx.x;
    for (int i = t; i < NBK; i += 256) { h[i] = 0; c2[i] = 0; }
    __syncthreads();
    int base = blockIdx.x * CHUNK;
    int end = min(base + CHUNK, N_EDGES);
    for (int e = base + t; e < end; e += 256)
        atomicAdd(&h[dst[e] >> BK_SHIFT], 1);
    __syncthreads();
    for (int i = t; i < NBK; i += 256)
        rb[i] = h[i] ? atomicAdd(&bucket_cur[i], h[i]) : 0;
    __syncthreads();
    for (int e = base + t; e < end; e += 256) {
        int d = dst[e];
        int b = d >> BK_SHIFT;
        int k = atomicAdd(&c2[b], 1);
        pairs[rb[b] + k] = (src[e] << BK_SHIFT) | (d & (BK_NODES - 1));
    }
}

// ----------------- P2: per-bucket CSR finalize (counts, scan, norms, fill)
__global__ __launch_bounds__(512) void k_bfill(const int* __restrict__ pairs,
                                               const int* __restrict__ bucket_cur,
                                               int* __restrict__ row_start,
                                               int* __restrict__ row_end,
                                               float* __restrict__ dis,
                                               int* __restrict__ csr_src) {
    __shared__ int cnt[BK_NODES];
    __shared__ int cur[BK_NODES];
    __shared__ int ts[512];
    int b = blockIdx.x, t = threadIdx.x;
    int node_base = b << BK_SHIFT;
    int lo = b * SLAB, hi = bucket_cur[b];

    if (t < BK_NODES) cnt[t] = 0;
    __syncthreads();
    for (int e = lo + t; e < hi; e += 512)
        atomicAdd(&cnt[pairs[e] & (BK_NODES - 1)], 1);
    __syncthreads();

    int a = (t < BK_NODES) ? cnt[t] : 0;
    ts[t] = a;
    __syncthreads();
    for (int off = 1; off < BK_NODES; off <<= 1) {
        int y = (t >= off) ? ts[t - off] : 0;
        __syncthreads();
        ts[t] += y;
        __syncthreads();
    }
    int row = lo + ts[t] - a;            // exclusive scan within slab
    if (t < BK_NODES) {
        cur[t] = row;
        int n = node_base + t;
        if (n < N_NODES) {
            row_start[n] = row;
            row_end[n]   = row + a;
            dis[n] = rsqrtf((float)(a + 1));   // deg incl. self-loop
        }
    }
    __syncthreads();

    for (int e = lo + t; e < hi; e += 512) {
        int p = pairs[e];
        int pos = atomicAdd(&cur[p & (BK_NODES - 1)], 1);
        csr_src[pos] = p >> BK_SHIFT;
    }
}

// Pre-swizzle W (fp32 [k][n]) into MFMA B-fragment order, fp16.
__global__ void k_wconv(const float* __restrict__ w0, const float* __restrict__ w1,
                        const float* __restrict__ w2, _Float16* __restrict__ wf) {
    int b = blockIdx.x, t = threadIdx.x;
    const float* W = (b == 0) ? w0 : (b == 1) ? w1 : w2;
    _Float16* dst = wf + (size_t)b * NF * NF;
    for (int idx = t; idx < NF * NF; idx += 256) {
        int k = idx >> 7, n = idx & 127;
        int nt = n >> 4, kc = k >> 5, quad = (k >> 3) & 3, j = k & 7;
        int lane = quad * 16 + (n & 15);
        dst[((nt * 4 + kc) * 64 + lane) * 8 + j] = (_Float16)W[idx];
    }
}

// ------------------------------------------------------------- MFMA GEMM
// H'[r][c] = dis[r] * sum_k act(X[r][k]) * W[k][c]; fp32 acc, fp16 out.
// Row-major H/Ah layout ([N][128] fp16).
template <bool ELU, bool FP32IN>
__global__ __launch_bounds__(256) void k_gemm(const void* __restrict__ Xv,
                                              const _Float16* __restrict__ WF,
                                              const float* __restrict__ dis,
                                              __half* __restrict__ H) {
    __shared__ _Float16 xs[64 * 136];
    const _Float16* Xh = (const _Float16*)Xv;
    const float*    Xf = (const float*)Xv;
    int t = threadIdx.x;
    int row0 = blockIdx.x * 64;
#pragma unroll
    for (int i = 0; i < 4; i++) {
        int f = i * 256 + t;              // 0..1023 : 64 rows x 16 half8
        int r = f >> 4, c = (f & 15) * 8;
        int gr = row0 + r;
        half8 v = {};
        if (gr < N_NODES) {
            if (FP32IN) {
                float4 v0 = *(const float4*)&Xf[(size_t)gr * NF + c];
                float4 v1 = *(const float4*)&Xf[(size_t)gr * NF + c + 4];
                v[0] = (_Float16)v0.x; v[1] = (_Float16)v0.y;
                v[2] = (_Float16)v0.z; v[3] = (_Float16)v0.w;
                v[4] = (_Float16)v1.x; v[5] = (_Float16)v1.y;
                v[6] = (_Float16)v1.z; v[7] = (_Float16)v1.w;
            } else {
                v = *(const half8*)&Xh[(size_t)gr * NF + c];
            }
        }
        if (ELU) {
#pragma unroll
            for (int j = 0; j < 8; j++) {
                float xv = (float)v[j];
                v[j] = (_Float16)(xv > 0.f ? xv : (expf(xv) - 1.f));
            }
        }
        *(half8*)&xs[r * 136 + c] = v;
    }
    __syncthreads();

    int w = t >> 6;              // wave id: rows w*16..w*16+15
    int lane = t & 63;
    int m = lane & 15, quad = lane >> 4;

    half8 a[4];
#pragma unroll
    for (int kc = 0; kc < 4; kc++)
        a[kc] = *(const half8*)&xs[(w * 16 + m) * 136 + kc * 32 + quad * 8];

    f32x4 acc[8];
#pragma unroll
    for (int nt = 0; nt < 8; nt++) {
        f32x4 c4 = {0.f, 0.f, 0.f, 0.f};
#pragma unroll
        for (int kc = 0; kc < 4; kc++) {
            half8 bf = *(const half8*)&WF[((nt * 4 + kc) * 64 + lane) * 8];
            c4 = __builtin_amdgcn_mfma_f32_16x16x32_f16(a[kc], bf, c4, 0, 0, 0);
        }
        acc[nt] = c4;
    }

    __syncthreads();                      // all waves done reading xs
#pragma unroll
    for (int reg = 0; reg < 4; reg++) {
        int r = w * 16 + quad * 4 + reg;
        int gr = row0 + r;
        float ds = (gr < N_NODES) ? dis[gr] : 0.f;
#pragma unroll
        for (int nt = 0; nt < 8; nt++)
            xs[r * 136 + nt * 16 + m] = (_Float16)(ds * acc[nt][reg]);
    }
    __syncthreads();
#pragma unroll
    for (int i = 0; i < 4; i++) {
        int f = i * 256 + t;
        int r = f >> 4, c = (f & 15) * 8;
        int gr = row0 + r;
        if (gr < N_NODES)
            *(half8*)&H[(size_t)gr * NF + c] = *(const half8*)&xs[r * 136 + c];
    }
}

// ------------------------------------------------------------- aggregation
// Round-2 inner loop VERBATIM (proven 62 µs); only the workgroup packing
// changes: 1024 threads = 64 nodes/block, grid 782. Every k_agg variant
// r0-r8 showed OccupancyPercent ~40% with all pipes idle regardless of
// VGPR/LDS/grid — hypothesis: per-CU workgroup-count scheduling cap on many
// small 256-thr blocks. Packing the same waves into 4x larger blocks should
// raise resident waves; latency-bound gather throughput scales with them.
template <bool POOL>
__global__ __launch_bounds__(1024) void k_agg(const __half* __restrict__ H,
                                              const float* __restrict__ bias,
                                              const int* __restrict__ row_start,
                                              const int* __restrict__ row_end,
                                              const int* __restrict__ csr_src,
                                              const float* __restrict__ dis,
                                              const int* __restrict__ batch,
                                              void* __restrict__ outv) {
    __shared__ float pacc[NF];
    const uint4* H16 = (const uint4*)H;     // 16 B = 8 halves; row stride 16
    int t = threadIdx.x;
    int node = blockIdx.x * AGG_NPB + (t >> 4);
    int l    = t & 15;                       // uint4 column within 256 B row
    bool active = node < N_NODES;

    if (POOL) {
        if (t < NF) pacc[t] = 0.f;
        __syncthreads();
    }

    float a[8] = {0.f, 0.f, 0.f, 0.f, 0.f, 0.f, 0.f, 0.f};
    if (active) {
        int rs = row_start[node], re = row_end[node];
        int e = rs;
        if (e + 7 < re) {
            int s[8];
#pragma unroll
            for (int j = 0; j < 8; j++) s[j] = csr_src[e + j];
            for (; e + 15 < re; e += 8) {
                int sn[8];
#pragma unroll
                for (int j = 0; j < 8; j++) sn[j] = csr_src[e + 8 + j];
                uint4 v[8];
#pragma unroll
                for (int j = 0; j < 8; j++) v[j] = H16[(size_t)s[j] * 16 + l];
#pragma unroll
                for (int j = 0; j < 8; j++) {
                    float2 f0 = __half22float2(*(__half2*)&v[j].x);
                    float2 f1 = __half22float2(*(__half2*)&v[j].y);
                    float2 f2 = __half22float2(*(__half2*)&v[j].z);
                    float2 f3 = __half22float2(*(__half2*)&v[j].w);
                    a[0] += f0.x; a[1] += f0.y; a[2] += f1.x; a[3] += f1.y;
                    a[4] += f2.x; a[5] += f2.y; a[6] += f3.x; a[7] += f3.y;
                }
#pragma unroll
                for (int j = 0; j < 8; j++) s[j] = sn[j];
            }
            {   // final full batch (indices already prefetched)
                uint4 v[8];
#pragma unroll
                for (int j = 0; j < 8; j++) v[j] = H16[(size_t)s[j] * 16 + l];
#pragma unroll
                for (int j = 0; j < 8; j++) {
                    float2 f0 = __half22float2(*(__half2*)&v[j].x);
                    float2 f1 = __half22float2(*(__half2*)&v[j].y);
                    float2 f2 = __half22float2(*(__half2*)&v[j].z);
                    float2 f3 = __half22float2(*(__half2*)&v[j].w);
                    a[0] += f0.x; a[1] += f0.y; a[2] += f1.x; a[3] += f1.y;
                    a[4] += f2.x; a[5] += f2.y; a[6] += f3.x; a[7] += f3.y;
                }
                e += 8;
            }
        }
        for (; e < re; e++) {               // tail (< 8 edges)
            uint4 v = H16[(size_t)csr_src[e] * 16 + l];
            float2 f0 = __half22float2(*(__half2*)&v.x);
            float2 f1 = __half22float2(*(__half2*)&v.y);
            float2 f2 = __half22float2(*(__half2*)&v.z);
            float2 f3 = __half22float2(*(__half2*)&v.w);
            a[0] += f0.x; a[1] += f0.y; a[2] += f1.x; a[3] += f1.y;
            a[4] += f2.x; a[5] += f2.y; a[6] += f3.x; a[7] += f3.y;
        }
        {   // self-loop term
            uint4 v = H16[(size_t)node * 16 + l];
            float2 f0 = __half22float2(*(__half2*)&v.x);
            float2 f1 = __half22float2(*(__half2*)&v.y);
            float2 f2 = __half22float2(*(__half2*)&v.z);
            float2 f3 = __half22float2(*(__half2*)&v.w);
            a[0] += f0.x; a[1] += f0.y; a[2] += f1.x; a[3] += f1.y;
            a[4] += f2.x; a[5] += f2.y; a[6] += f3.x; a[7] += f3.y;
        }
    }

    float o[8] = {0.f, 0.f, 0.f, 0.f, 0.f, 0.f, 0.f, 0.f};
    if (active) {
        float di = dis[node];
        float4 b0 = *(const float4*)&bias[l * 8];
        float4 b1 = *(const float4*)&bias[l * 8 + 4];
        o[0] = a[0] * di + b0.x; o[1] = a[1] * di + b0.y;
        o[2] = a[2] * di + b0.z; o[3] = a[3] * di + b0.w;
        o[4] = a[4] * di + b1.x; o[5] = a[5] * di + b1.y;
        o[6] = a[6] * di + b1.z; o[7] = a[7] * di + b1.w;
        if (!POOL) {
            uint4 pk;
            *(__half2*)&pk.x = __floats2half2_rn(o[0], o[1]);
            *(__half2*)&pk.y = __floats2half2_rn(o[2], o[3]);
            *(__half2*)&pk.z = __floats2half2_rn(o[4], o[5]);
            *(__half2*)&pk.w = __floats2half2_rn(o[6], o[7]);
            ((uint4*)outv)[(size_t)node * 16 + l] = pk;
        }
    }

    if (POOL) {
        float* sums = (float*)outv;
        int first = blockIdx.x * AGG_NPB;
        int last  = min(first + AGG_NPB - 1, N_NODES - 1);
        int g0 = batch[first], gl = batch[last];
        if (g0 == gl) {                  // block-uniform fast path
#pragma unroll
            for (int k = 0; k < 8; k++) {
                o[k] += __shfl_xor(o[k], 16);
                o[k] += __shfl_xor(o[k], 32);
            }
            if ((t & 63) < 16) {         // per-wave partial into LDS
#pragma unroll
                for (int k = 0; k < 8; k++)
                    atomicAdd(&pacc[l * 8 + k], o[k]);
            }
            __syncthreads();
            if (t < NF) atomicAdd(&sums[g0 * NF + t], pacc[t]);
        } else if (active) {             // graph-boundary block (63/782)
            int g = batch[node];
#pragma unroll
            for (int k = 0; k < 8; k++)
                atomicAdd(&sums[g * NF + l * 8 + k], o[k]);
        }
    }
}

// ---------------------------------------------------------------- heads
__global__ void k_head(const float* __restrict__ sums, const int* __restrict__ batch,
                       const float* __restrict__ wc, const float* __restrict__ bc,
                       const float* __restrict__ wr, const float* __restrict__ br,
                       float* __restrict__ out) {
    __shared__ float p[128];
    __shared__ int cnt_s;
    int g = blockIdx.x, c = threadIdx.x;
    if (c == 0) {
        int lo = 0, hi = N_NODES;
        while (lo < hi) { int m = (lo + hi) >> 1; if (batch[m] < g) lo = m + 1; else hi = m; }
        int s0 = lo;
        lo = 0; hi = N_NODES;
        while (lo < hi) { int m = (lo + hi) >> 1; if (batch[m] < g + 1) lo = m + 1; else hi = m; }
        cnt_s = lo - s0;
    }
    __syncthreads();
    float cnt = (float)max(cnt_s, 1);
    float pv = sums[g * NF + c] / cnt;
    p[c] = pv;
    out[g * NF + c] = pv;
    __syncthreads();
    if (c < N_CLASSES) {
        float d = bc[c];
        for (int k = 0; k < NF; k++) d += p[k] * wc[k * N_CLASSES + c];
        out[N_GRAPHS * NF + g * N_CLASSES + c] = d;
    }
    if (c == N_CLASSES) {
        float d = br[0];
        for (int k = 0; k < NF; k++) d += p[k] * wr[k];
        out[N_GRAPHS * NF + N_GRAPHS * N_CLASSES + g] = d;
    }
}

// ================================================================= launch
extern "C" void kernel_launch(void* const* d_in, const int* in_sizes, int n_in,
                              void* d_out, int out_size, void* d_ws, size_t ws_size,
                              hipStream_t stream) {
    const float* x     = (const float*)d_in[0];
    const int*   ei    = (const int*)d_in[1];
    const int*   batch = (const int*)d_in[2];
    const float* w0 = (const float*)d_in[3];
    const float* b0 = (const float*)d_in[4];
    const float* w1 = (const float*)d_in[5];
    const float* b1 = (const float*)d_in[6];
    const float* w2 = (const float*)d_in[7];
    const float* b2 = (const float*)d_in[8];
    const float* wc = (const float*)d_in[9];
    const float* bc = (const float*)d_in[10];
    const float* wr = (const float*)d_in[11];
    const float* br = (const float*)d_in[12];
    const int* srcp = ei;
    const int* dstp = ei + N_EDGES;
    float* out = (float*)d_out;

    char* ws = (char*)d_ws;
    size_t off = 0;
    auto alloc = [&](size_t bytes) -> void* {
        void* p = ws + off;
        off = (off + bytes + 255) & ~(size_t)255;
        return p;
    };
    int*      row_start  = (int*)alloc(N_NODES * 4);
    int*      row_end    = (int*)alloc(N_NODES * 4);
    int*      bucket_cur = (int*)alloc(NBK * 4);
    float*    dis        = (float*)alloc(N_NODES * 4);
    int*      csr_src    = (int*)alloc((size_t)NBK * SLAB * 4);   // slab layout
    __half*   Hbuf       = (__half*)alloc((size_t)N_NODES * NF * 2);
    _Float16* Ah         = (_Float16*)alloc((size_t)N_NODES * NF * 2);
    _Float16* wf         = (_Float16*)alloc((size_t)3 * NF * NF * 2);
    float*    sums       = (float*)alloc(N_GRAPHS * NF * 4);
    (void)ws_size;
    // pairs (8 MB slab) aliases Hbuf (12.8 MB): dead after k_bfill; Hbuf is
    // first written by gemm0 (stream-ordered after bfill).
    int* pairs = (int*)Hbuf;

    k_zero<<<32, 256, 0, stream>>>(bucket_cur, sums);
    k_bscatter<<<NCHUNKS, 256, 0, stream>>>(srcp, dstp, bucket_cur, pairs);
    k_bfill<<<NBK, 512, 0, stream>>>(pairs, bucket_cur, row_start, row_end, dis, csr_src);
    k_wconv<<<3, 256, 0, stream>>>(w0, w1, w2, wf);

    const int gemm_grid = (N_NODES + 63) / 64;   // 782

    // layer 0 (fp32 x read directly)
    k_gemm<false, true><<<gemm_grid, 256, 0, stream>>>(x, wf, dis, Hbuf);
    k_agg<false><<<AGG_GRID, 1024, 0, stream>>>(Hbuf, b0, row_start, row_end, csr_src, dis, batch, Ah);
    // layer 1
    k_gemm<true, false><<<gemm_grid, 256, 0, stream>>>(Ah, wf + NF * NF, dis, Hbuf);
    k_agg<false><<<AGG_GRID, 1024, 0, stream>>>(Hbuf, b1, row_start, row_end, csr_src, dis, batch, Ah);
    // layer 2 (pooling fused; no per-node fp32 output)
    k_gemm<true, false><<<gemm_grid, 256, 0, stream>>>(Ah, wf + 2 * NF * NF, dis, Hbuf);
    k_agg<true><<<AGG_GRID, 1024, 0, stream>>>(Hbuf, b2, row_start, row_end, csr_src, dis, batch, sums);

    k_head<<<N_GRAPHS, 128, 0, stream>>>(sums, batch, wc, bc, wr, br, out);
}

// Round 10
// 359.516 us; speedup vs baseline: 1.1799x; 1.1799x over previous
//
#include <hip/hip_runtime.h>
#include <hip/hip_fp16.h>
#include <math.h>

#define N_NODES   50000
#define N_EDGES   1600000
#define NF        128
#define N_GRAPHS  64
#define N_CLASSES 10

#define NBK       391       // buckets: dst>>7, 128 nodes each (391*128 = 50048)
#define BK_SHIFT  7
#define BK_NODES  128
#define SLAB      5120      // slab capacity/bucket: mean 4096, sigma~64, +16s
#define CHUNK     8192      // bigger chunks: reservation chain depth 391 -> 196
#define NCHUNKS   ((N_EDGES + CHUNK - 1) / CHUNK)   // 196
#define EPT       (CHUNK / 512)                      // 16 edges/thread

#define AGG_NPB   16        // nodes per k_agg block: 4 nodes/wave, 16 lanes x 16B
#define AGG_GRID  ((N_NODES + AGG_NPB - 1) / AGG_NPB)   // 3125

typedef _Float16 half8 __attribute__((ext_vector_type(8)));
typedef float f32x4 __attribute__((ext_vector_type(4)));

// ------------------------------------------------------------ zero / init
__global__ void k_zero(int* __restrict__ bucket_cur, float* __restrict__ sums) {
    int i = blockIdx.x * 256 + threadIdx.x;
    if (i < NBK) bucket_cur[i] = i * SLAB;
    if (i < N_GRAPHS * NF) sums[i] = 0.f;
}

// ------------- P1: scatter packed (src<<7|dstlocal) into bucket slabs
// CHUNK 8192 / 512 thr (196 blocks): every block atomicAdds the SAME 391
// bucket_cur addresses, so the per-address cross-XCD RMW chain depth equals
// the block count — halved vs 391-block config (~150-300 cy per same-line
// RMW). dst values are register-cached across the two passes (one less
// 6.4 MB global re-read).
__global__ __launch_bounds__(512) void k_bscatter(const int* __restrict__ src,
                                                  const int* __restrict__ dst,
                                                  int* __restrict__ bucket_cur,
                                                  int* __restrict__ pairs) {
    __shared__ int h[NBK], rb[NBK], c2[NBK];
    int t = threadIdx.x;
    for (int i = t; i < NBK; i += 512) { h[i] = 0; c2[i] = 0; }
    __syncthreads();
    int base = blockIdx.x * CHUNK;
    int end = min(base + CHUNK, N_EDGES);
    int dcache[EPT];
    int nv = 0;
    for (int e = base + t; e < end; e += 512) {
        int d = dst[e];
        dcache[nv++] = d;
        atomicAdd(&h[d >> BK_SHIFT], 1);
    }
    __syncthreads();
    for (int i = t; i < NBK; i += 512)
        rb[i] = h[i] ? atomicAdd(&bucket_cur[i], h[i]) : 0;
    __syncthreads();
    nv = 0;
    for (int e = base + t; e < end; e += 512) {
        int d = dcache[nv++];
        int b = d >> BK_SHIFT;
        int k = atomicAdd(&c2[b], 1);
        pairs[rb[b] + k] = (src[e] << BK_SHIFT) | (d & (BK_NODES - 1));
    }
}

// ----------------- P2: per-bucket CSR finalize (counts, scan, norms, fill)
__global__ __launch_bounds__(512) void k_bfill(const int* __restrict__ pairs,
                                               const int* __restrict__ bucket_cur,
                                               int* __restrict__ row_start,
                                               int* __restrict__ row_end,
                                               float* __restrict__ dis,
                                               int* __restrict__ csr_src) {
    __shared__ int cnt[BK_NODES];
    __shared__ int cur[BK_NODES];
    __shared__ int ts[512];
    int b = blockIdx.x, t = threadIdx.x;
    int node_base = b << BK_SHIFT;
    int lo = b * SLAB, hi = bucket_cur[b];

    if (t < BK_NODES) cnt[t] = 0;
    __syncthreads();
    for (int e = lo + t; e < hi; e += 512)
        atomicAdd(&cnt[pairs[e] & (BK_NODES - 1)], 1);
    __syncthreads();

    int a = (t < BK_NODES) ? cnt[t] : 0;
    ts[t] = a;
    __syncthreads();
    for (int off = 1; off < BK_NODES; off <<= 1) {
        int y = (t >= off) ? ts[t - off] : 0;
        __syncthreads();
        ts[t] += y;
        __syncthreads();
    }
    int row = lo + ts[t] - a;            // exclusive scan within slab
    if (t < BK_NODES) {
        cur[t] = row;
        int n = node_base + t;
        if (n < N_NODES) {
            row_start[n] = row;
            row_end[n]   = row + a;
            dis[n] = rsqrtf((float)(a + 1));   // deg incl. self-loop
        }
    }
    __syncthreads();

    for (int e = lo + t; e < hi; e += 512) {
        int p = pairs[e];
        int pos = atomicAdd(&cur[p & (BK_NODES - 1)], 1);
        csr_src[pos] = p >> BK_SHIFT;
    }
}

// Pre-swizzle W (fp32 [k][n]) into MFMA B-fragment order, fp16.
__global__ void k_wconv(const float* __restrict__ w0, const float* __restrict__ w1,
                        const float* __restrict__ w2, _Float16* __restrict__ wf) {
    int b = blockIdx.x, t = threadIdx.x;
    const float* W = (b == 0) ? w0 : (b == 1) ? w1 : w2;
    _Float16* dst = wf + (size_t)b * NF * NF;
    for (int idx = t; idx < NF * NF; idx += 256) {
        int k = idx >> 7, n = idx & 127;
        int nt = n >> 4, kc = k >> 5, quad = (k >> 3) & 3, j = k & 7;
        int lane = quad * 16 + (n & 15);
        dst[((nt * 4 + kc) * 64 + lane) * 8 + j] = (_Float16)W[idx];
    }
}

// ------------------------------------------------------------- MFMA GEMM
// H'[r][c] = dis[r] * sum_k act(X[r][k]) * W[k][c]; fp32 acc, fp16 out.
// Row-major H/Ah layout ([N][128] fp16).
template <bool ELU, bool FP32IN>
__global__ __launch_bounds__(256) void k_gemm(const void* __restrict__ Xv,
                                              const _Float16* __restrict__ WF,
                                              const float* __restrict__ dis,
                                              __half* __restrict__ H) {
    __shared__ _Float16 xs[64 * 136];
    const _Float16* Xh = (const _Float16*)Xv;
    const float*    Xf = (const float*)Xv;
    int t = threadIdx.x;
    int row0 = blockIdx.x * 64;
#pragma unroll
    for (int i = 0; i < 4; i++) {
        int f = i * 256 + t;              // 0..1023 : 64 rows x 16 half8
        int r = f >> 4, c = (f & 15) * 8;
        int gr = row0 + r;
        half8 v = {};
        if (gr < N_NODES) {
            if (FP32IN) {
                float4 v0 = *(const float4*)&Xf[(size_t)gr * NF + c];
                float4 v1 = *(const float4*)&Xf[(size_t)gr * NF + c + 4];
                v[0] = (_Float16)v0.x; v[1] = (_Float16)v0.y;
                v[2] = (_Float16)v0.z; v[3] = (_Float16)v0.w;
                v[4] = (_Float16)v1.x; v[5] = (_Float16)v1.y;
                v[6] = (_Float16)v1.z; v[7] = (_Float16)v1.w;
            } else {
                v = *(const half8*)&Xh[(size_t)gr * NF + c];
            }
        }
        if (ELU) {
#pragma unroll
            for (int j = 0; j < 8; j++) {
                float xv = (float)v[j];
                v[j] = (_Float16)(xv > 0.f ? xv : (expf(xv) - 1.f));
            }
        }
        *(half8*)&xs[r * 136 + c] = v;
    }
    __syncthreads();

    int w = t >> 6;              // wave id: rows w*16..w*16+15
    int lane = t & 63;
    int m = lane & 15, quad = lane >> 4;

    half8 a[4];
#pragma unroll
    for (int kc = 0; kc < 4; kc++)
        a[kc] = *(const half8*)&xs[(w * 16 + m) * 136 + kc * 32 + quad * 8];

    f32x4 acc[8];
#pragma unroll
    for (int nt = 0; nt < 8; nt++) {
        f32x4 c4 = {0.f, 0.f, 0.f, 0.f};
#pragma unroll
        for (int kc = 0; kc < 4; kc++) {
            half8 bf = *(const half8*)&WF[((nt * 4 + kc) * 64 + lane) * 8];
            c4 = __builtin_amdgcn_mfma_f32_16x16x32_f16(a[kc], bf, c4, 0, 0, 0);
        }
        acc[nt] = c4;
    }

    __syncthreads();                      // all waves done reading xs
#pragma unroll
    for (int reg = 0; reg < 4; reg++) {
        int r = w * 16 + quad * 4 + reg;
        int gr = row0 + r;
        float ds = (gr < N_NODES) ? dis[gr] : 0.f;
#pragma unroll
        for (int nt = 0; nt < 8; nt++)
            xs[r * 136 + nt * 16 + m] = (_Float16)(ds * acc[nt][reg]);
    }
    __syncthreads();
#pragma unroll
    for (int i = 0; i < 4; i++) {
        int f = i * 256 + t;
        int r = f >> 4, c = (f & 15) * 8;
        int gr = row0 + r;
        if (gr < N_NODES)
            *(half8*)&H[(size_t)gr * NF + c] = *(const half8*)&xs[r * 136 + c];
    }
}

// ------------------------------------------------------------- aggregation
// Round-2 structure verbatim (proven 62 µs — the floor across 5 falsified
// alternatives: slicing r3/r4, deep pipeline r5, src-sort r8, 1024-thr r9).
// Model: per-CU L2-miss concurrency bound — 9.3K misses/CU x ~16 cy = 62 µs.
template <bool POOL>
__global__ __launch_bounds__(256) void k_agg(const __half* __restrict__ H,
                                             const float* __restrict__ bias,
                                             const int* __restrict__ row_start,
                                             const int* __restrict__ row_end,
                                             const int* __restrict__ csr_src,
                                             const float* __restrict__ dis,
                                             const int* __restrict__ batch,
                                             void* __restrict__ outv) {
    __shared__ float pacc[NF];
    const uint4* H16 = (const uint4*)H;     // 16 B = 8 halves; row stride 16
    int t = threadIdx.x;
    int node = blockIdx.x * AGG_NPB + (t >> 4);
    int l    = t & 15;                       // uint4 column within 256 B row
    bool active = node < N_NODES;

    if (POOL) {
        if (t < NF) pacc[t] = 0.f;
        __syncthreads();
    }

    float a[8] = {0.f, 0.f, 0.f, 0.f, 0.f, 0.f, 0.f, 0.f};
    if (active) {
        int rs = row_start[node], re = row_end[node];
        int e = rs;
        if (e + 7 < re) {
            int s[8];
#pragma unroll
            for (int j = 0; j < 8; j++) s[j] = csr_src[e + j];
            for (; e + 15 < re; e += 8) {
                int sn[8];
#pragma unroll
                for (int j = 0; j < 8; j++) sn[j] = csr_src[e + 8 + j];
                uint4 v[8];
#pragma unroll
                for (int j = 0; j < 8; j++) v[j] = H16[(size_t)s[j] * 16 + l];
#pragma unroll
                for (int j = 0; j < 8; j++) {
                    float2 f0 = __half22float2(*(__half2*)&v[j].x);
                    float2 f1 = __half22float2(*(__half2*)&v[j].y);
                    float2 f2 = __half22float2(*(__half2*)&v[j].z);
                    float2 f3 = __half22float2(*(__half2*)&v[j].w);
                    a[0] += f0.x; a[1] += f0.y; a[2] += f1.x; a[3] += f1.y;
                    a[4] += f2.x; a[5] += f2.y; a[6] += f3.x; a[7] += f3.y;
                }
#pragma unroll
                for (int j = 0; j < 8; j++) s[j] = sn[j];
            }
            {   // final full batch (indices already prefetched)
                uint4 v[8];
#pragma unroll
                for (int j = 0; j < 8; j++) v[j] = H16[(size_t)s[j] * 16 + l];
#pragma unroll
                for (int j = 0; j < 8; j++) {
                    float2 f0 = __half22float2(*(__half2*)&v[j].x);
                    float2 f1 = __half22float2(*(__half2*)&v[j].y);
                    float2 f2 = __half22float2(*(__half2*)&v[j].z);
                    float2 f3 = __half22float2(*(__half2*)&v[j].w);
                    a[0] += f0.x; a[1] += f0.y; a[2] += f1.x; a[3] += f1.y;
                    a[4] += f2.x; a[5] += f2.y; a[6] += f3.x; a[7] += f3.y;
                }
                e += 8;
            }
        }
        for (; e < re; e++) {               // tail (< 8 edges)
            uint4 v = H16[(size_t)csr_src[e] * 16 + l];
            float2 f0 = __half22float2(*(__half2*)&v.x);
            float2 f1 = __half22float2(*(__half2*)&v.y);
            float2 f2 = __half22float2(*(__half2*)&v.z);
            float2 f3 = __half22float2(*(__half2*)&v.w);
            a[0] += f0.x; a[1] += f0.y; a[2] += f1.x; a[3] += f1.y;
            a[4] += f2.x; a[5] += f2.y; a[6] += f3.x; a[7] += f3.y;
        }
        {   // self-loop term
            uint4 v = H16[(size_t)node * 16 + l];
            float2 f0 = __half22float2(*(__half2*)&v.x);
            float2 f1 = __half22float2(*(__half2*)&v.y);
            float2 f2 = __half22float2(*(__half2*)&v.z);
            float2 f3 = __half22float2(*(__half2*)&v.w);
            a[0] += f0.x; a[1] += f0.y; a[2] += f1.x; a[3] += f1.y;
            a[4] += f2.x; a[5] += f2.y; a[6] += f3.x; a[7] += f3.y;
        }
    }

    float o[8] = {0.f, 0.f, 0.f, 0.f, 0.f, 0.f, 0.f, 0.f};
    if (active) {
        float di = dis[node];
        float4 b0 = *(const float4*)&bias[l * 8];
        float4 b1 = *(const float4*)&bias[l * 8 + 4];
        o[0] = a[0] * di + b0.x; o[1] = a[1] * di + b0.y;
        o[2] = a[2] * di + b0.z; o[3] = a[3] * di + b0.w;
        o[4] = a[4] * di + b1.x; o[5] = a[5] * di + b1.y;
        o[6] = a[6] * di + b1.z; o[7] = a[7] * di + b1.w;
        if (!POOL) {
            uint4 pk;
            *(__half2*)&pk.x = __floats2half2_rn(o[0], o[1]);
            *(__half2*)&pk.y = __floats2half2_rn(o[2], o[3]);
            *(__half2*)&pk.z = __floats2half2_rn(o[4], o[5]);
            *(__half2*)&pk.w = __floats2half2_rn(o[6], o[7]);
            ((uint4*)outv)[(size_t)node * 16 + l] = pk;
        }
    }

    if (POOL) {
        float* sums = (float*)outv;
        int first = blockIdx.x * AGG_NPB;
        int last  = min(first + AGG_NPB - 1, N_NODES - 1);
        int g0 = batch[first], gl = batch[last];
        if (g0 == gl) {                  // block-uniform fast path
#pragma unroll
            for (int k = 0; k < 8; k++) {
                o[k] += __shfl_xor(o[k], 16);
                o[k] += __shfl_xor(o[k], 32);
            }
            if ((t & 63) < 16) {
#pragma unroll
                for (int k = 0; k < 8; k++)
                    atomicAdd(&pacc[l * 8 + k], o[k]);
            }
            __syncthreads();
            if (t < NF) atomicAdd(&sums[g0 * NF + t], pacc[t]);
        } else if (active) {             // rare graph-boundary block
            int g = batch[node];
#pragma unroll
            for (int k = 0; k < 8; k++)
                atomicAdd(&sums[g * NF + l * 8 + k], o[k]);
        }
    }
}

// ---------------------------------------------------------------- heads
__global__ void k_head(const float* __restrict__ sums, const int* __restrict__ batch,
                       const float* __restrict__ wc, const float* __restrict__ bc,
                       const float* __restrict__ wr, const float* __restrict__ br,
                       float* __restrict__ out) {
    __shared__ float p[128];
    __shared__ int cnt_s;
    int g = blockIdx.x, c = threadIdx.x;
    if (c == 0) {
        int lo = 0, hi = N_NODES;
        while (lo < hi) { int m = (lo + hi) >> 1; if (batch[m] < g) lo = m + 1; else hi = m; }
        int s0 = lo;
        lo = 0; hi = N_NODES;
        while (lo < hi) { int m = (lo + hi) >> 1; if (batch[m] < g + 1) lo = m + 1; else hi = m; }
        cnt_s = lo - s0;
    }
    __syncthreads();
    float cnt = (float)max(cnt_s, 1);
    float pv = sums[g * NF + c] / cnt;
    p[c] = pv;
    out[g * NF + c] = pv;
    __syncthreads();
    if (c < N_CLASSES) {
        float d = bc[c];
        for (int k = 0; k < NF; k++) d += p[k] * wc[k * N_CLASSES + c];
        out[N_GRAPHS * NF + g * N_CLASSES + c] = d;
    }
    if (c == N_CLASSES) {
        float d = br[0];
        for (int k = 0; k < NF; k++) d += p[k] * wr[k];
        out[N_GRAPHS * NF + N_GRAPHS * N_CLASSES + g] = d;
    }
}

// ================================================================= launch
extern "C" void kernel_launch(void* const* d_in, const int* in_sizes, int n_in,
                              void* d_out, int out_size, void* d_ws, size_t ws_size,
                              hipStream_t stream) {
    const float* x     = (const float*)d_in[0];
    const int*   ei    = (const int*)d_in[1];
    const int*   batch = (const int*)d_in[2];
    const float* w0 = (const float*)d_in[3];
    const float* b0 = (const float*)d_in[4];
    const float* w1 = (const float*)d_in[5];
    const float* b1 = (const float*)d_in[6];
    const float* w2 = (const float*)d_in[7];
    const float* b2 = (const float*)d_in[8];
    const float* wc = (const float*)d_in[9];
    const float* bc = (const float*)d_in[10];
    const float* wr = (const float*)d_in[11];
    const float* br = (const float*)d_in[12];
    const int* srcp = ei;
    const int* dstp = ei + N_EDGES;
    float* out = (float*)d_out;

    char* ws = (char*)d_ws;
    size_t off = 0;
    auto alloc = [&](size_t bytes) -> void* {
        void* p = ws + off;
        off = (off + bytes + 255) & ~(size_t)255;
        return p;
    };
    int*      row_start  = (int*)alloc(N_NODES * 4);
    int*      row_end    = (int*)alloc(N_NODES * 4);
    int*      bucket_cur = (int*)alloc(NBK * 4);
    float*    dis        = (float*)alloc(N_NODES * 4);
    int*      csr_src    = (int*)alloc((size_t)NBK * SLAB * 4);   // slab layout
    __half*   Hbuf       = (__half*)alloc((size_t)N_NODES * NF * 2);
    _Float16* Ah         = (_Float16*)alloc((size_t)N_NODES * NF * 2);
    _Float16* wf         = (_Float16*)alloc((size_t)3 * NF * NF * 2);
    float*    sums       = (float*)alloc(N_GRAPHS * NF * 4);
    (void)ws_size;
    // pairs (8 MB slab) aliases Hbuf (12.8 MB): dead after k_bfill; Hbuf is
    // first written by gemm0 (stream-ordered after bfill).
    int* pairs = (int*)Hbuf;

    k_zero<<<32, 256, 0, stream>>>(bucket_cur, sums);
    k_bscatter<<<NCHUNKS, 512, 0, stream>>>(srcp, dstp, bucket_cur, pairs);
    k_bfill<<<NBK, 512, 0, stream>>>(pairs, bucket_cur, row_start, row_end, dis, csr_src);
    k_wconv<<<3, 256, 0, stream>>>(w0, w1, w2, wf);

    const int gemm_grid = (N_NODES + 63) / 64;   // 782

    // layer 0 (fp32 x read directly)
    k_gemm<false, true><<<gemm_grid, 256, 0, stream>>>(x, wf, dis, Hbuf);
    k_agg<false><<<AGG_GRID, 256, 0, stream>>>(Hbuf, b0, row_start, row_end, csr_src, dis, batch, Ah);
    // layer 1
    k_gemm<true, false><<<gemm_grid, 256, 0, stream>>>(Ah, wf + NF * NF, dis, Hbuf);
    k_agg<false><<<AGG_GRID, 256, 0, stream>>>(Hbuf, b1, row_start, row_end, csr_src, dis, batch, Ah);
    // layer 2 (pooling fused; no per-node fp32 output)
    k_gemm<true, false><<<gemm_grid, 256, 0, stream>>>(Ah, wf + 2 * NF * NF, dis, Hbuf);
    k_agg<true><<<AGG_GRID, 256, 0, stream>>>(Hbuf, b2, row_start, row_end, csr_src, dis, batch, sums);

    k_head<<<N_GRAPHS, 128, 0, stream>>>(sums, batch, wc, bc, wr, br, out);
}